// Round 1
// baseline (127.057 us; speedup 1.0000x reference)
//
#include <hip/hip_runtime.h>

// VectorQuantizer: B=32, D=64, H=64, W=64 -> N=131072 pixels; K=512 codes.
// out[0] = loss = 1.25 * mean((E[idx]-z)^2); out[1..] = Zq in [B,D,H,W].
// Strategy: bf16 MFMA 16x16x32 for the N x K x 64 distance GEMM (argmin only
// needs e_norm - 2*z.e since ||z||^2 is constant per pixel), fp32 everywhere
// that touches the output values / loss.

typedef __bf16 bf16x8 __attribute__((ext_vector_type(8)));
typedef __bf16 bf16x4 __attribute__((ext_vector_type(4)));
typedef float  f32x4  __attribute__((ext_vector_type(4)));

#define N_PIX   131072
#define KCODES  512
#define LOSS_SCALE (1.25f / 8388608.f)   // 1.25 / (N*D)

// ---------------- prep: E fp32 -> bf16 rows, e_norm, zero loss --------------
__global__ __launch_bounds__(256) void vq_prep(const float* __restrict__ E,
                                               __bf16* __restrict__ E16,
                                               float* __restrict__ e_norm,
                                               float* __restrict__ out) {
  int g = blockIdx.x * 256 + threadIdx.x;          // 8192 threads, 4 elems each
  if (g == 0) out[0] = 0.f;
  float4 v = ((const float4*)E)[g];
  float ss = v.x * v.x + v.y * v.y + v.z * v.z + v.w * v.w;
  // 16 consecutive threads cover one code row (64 floats)
  #pragma unroll
  for (int off = 1; off < 16; off <<= 1) ss += __shfl_xor(ss, off);
  if ((g & 15) == 0) e_norm[g >> 4] = ss;
  bf16x4 b;
  b[0] = (__bf16)v.x; b[1] = (__bf16)v.y; b[2] = (__bf16)v.z; b[3] = (__bf16)v.w;
  ((bf16x4*)E16)[g] = b;
}

// ---------------- main ------------------------------------------------------
__global__ __launch_bounds__(256) void vq_main(const float* __restrict__ in,
                                               const float* __restrict__ E,
                                               const __bf16* __restrict__ E16,
                                               const float* __restrict__ e_norm,
                                               float* __restrict__ out) {
  // LDS: Z tile 64 px x 64 dims bf16, rows padded to 72 elems (144 B, 16B-aligned)
  __shared__ __bf16 Zl[64 * 72];
  __shared__ float  znp[4 * 64];          // per-(wave,pixel) |z|^2 partials
  __shared__ unsigned keys[4 * 64];       // per-(wave,pixel) packed (dist,idx)
  __shared__ int    idx_l[64];

  const int t    = threadIdx.x;
  const int lane = t & 63;
  const int w    = t >> 6;                // wave id 0..3
  const int blk  = blockIdx.x;            // 2048 blocks, 64 px each
  const int bb   = blk >> 6;              // batch index (64 blocks per slab)
  const int hw0  = (blk & 63) << 6;
  const int base = bb * 262144 + hw0;     // elem offset of (b, d=0, hw0)

  // ---- stage Z: pixel = lane, wave w loads dim groups w*8.. and (w+4)*8..
  {
    float f0[8], f1[8], ss = 0.f;
    #pragma unroll
    for (int j = 0; j < 8; ++j) {
      f0[j] = in[base + (w * 8 + j) * 4096 + lane];
      f1[j] = in[base + ((w + 4) * 8 + j) * 4096 + lane];
    }
    bf16x8 v0, v1;
    #pragma unroll
    for (int j = 0; j < 8; ++j) {
      ss += f0[j] * f0[j] + f1[j] * f1[j];
      v0[j] = (__bf16)f0[j];
      v1[j] = (__bf16)f1[j];
    }
    *(bf16x8*)&Zl[lane * 72 + w * 8]      = v0;
    *(bf16x8*)&Zl[lane * 72 + 32 + w * 8] = v1;
    znp[w * 64 + lane] = ss;
  }
  __syncthreads();

  const int m16 = lane & 15, q = lane >> 4;

  // A fragments: 4 pixel-tiles x 2 k-halves, reused across all code tiles
  bf16x8 A[4][2];
  #pragma unroll
  for (int pt = 0; pt < 4; ++pt) {
    int p = pt * 16 + m16;
    A[pt][0] = *(const bf16x8*)&Zl[p * 72 + q * 8];
    A[pt][1] = *(const bf16x8*)&Zl[p * 72 + 32 + q * 8];
  }

  float mn[4][4];
  int   id[4][4];
  #pragma unroll
  for (int pt = 0; pt < 4; ++pt)
    #pragma unroll
    for (int r = 0; r < 4; ++r) { mn[pt][r] = 3.4e38f; id[pt][r] = 0; }

  // wave w owns codes [w*128, w*128+128): 8 code tiles of 16
  const int cbase = w * 128 + m16;
  bf16x8 B0 = *(const bf16x8*)(E16 + cbase * 64 + q * 8);
  bf16x8 B1 = *(const bf16x8*)(E16 + cbase * 64 + 32 + q * 8);
  float  en = e_norm[cbase];

  #pragma unroll
  for (int ct = 0; ct < 8; ++ct) {
    bf16x8 nB0, nB1; float nen;
    if (ct < 7) {                         // 1-deep prefetch of next B tile
      int nc = cbase + (ct + 1) * 16;
      nB0 = *(const bf16x8*)(E16 + nc * 64 + q * 8);
      nB1 = *(const bf16x8*)(E16 + nc * 64 + 32 + q * 8);
      nen = e_norm[nc];
    }
    const int c = cbase + ct * 16;        // this lane's column code
    #pragma unroll
    for (int pt = 0; pt < 4; ++pt) {
      f32x4 acc = {0.f, 0.f, 0.f, 0.f};
      acc = __builtin_amdgcn_mfma_f32_16x16x32_bf16(A[pt][0], B0, acc, 0, 0, 0);
      acc = __builtin_amdgcn_mfma_f32_16x16x32_bf16(A[pt][1], B1, acc, 0, 0, 0);
      // D layout: col = lane&15 (code), row = q*4+r (pixel pt*16+q*4+r)
      #pragma unroll
      for (int r = 0; r < 4; ++r) {
        float dist = fmaf(-2.f, acc[r], en);
        bool lt = dist < mn[pt][r];
        mn[pt][r] = lt ? dist : mn[pt][r];
        id[pt][r] = lt ? c    : id[pt][r];
      }
    }
    if (ct < 7) { B0 = nB0; B1 = nB1; en = nen; }
  }

  // ---- merge across the 16 columns: monotonic key = order-preserving uint,
  // low 9 bits replaced by code idx (<= 512-ulp perturbation, harmless)
  #pragma unroll
  for (int pt = 0; pt < 4; ++pt)
    #pragma unroll
    for (int r = 0; r < 4; ++r) {
      unsigned u = __float_as_uint(mn[pt][r]);
      unsigned s = (u & 0x80000000u) ? 0xFFFFFFFFu : 0x80000000u;
      unsigned key = ((u ^ s) & 0xFFFFFE00u) | (unsigned)id[pt][r];
      #pragma unroll
      for (int off = 1; off < 16; off <<= 1) {
        unsigned o = __shfl_xor(key, off);
        key = (o < key) ? o : key;
      }
      if (m16 == 0) keys[w * 64 + pt * 16 + q * 4 + r] = key;
    }
  __syncthreads();

  // ---- final per-pixel merge across waves + loss (wave 0 only)
  if (t < 64) {
    unsigned k0 = keys[t], k1 = keys[64 + t], k2 = keys[128 + t], k3 = keys[192 + t];
    unsigned km = k1 < k0 ? k1 : k0;
    unsigned kn = k3 < k2 ? k3 : k2;
    km = kn < km ? kn : km;
    int code = (int)(km & 511u);
    idx_l[t] = code;
    unsigned ub = (km >= 0x80000000u) ? (km ^ 0x80000000u) : ~km;
    float dist = __uint_as_float(ub);
    float zn = znp[t] + znp[64 + t] + znp[128 + t] + znp[192 + t];
    float md = zn + dist;                 // = min_k ||z - e_k||^2
    #pragma unroll
    for (int off = 1; off < 64; off <<= 1) md += __shfl_xor(md, off);
    if (t == 0) atomicAdd(out, md * LOSS_SCALE);
  }
  __syncthreads();

  // ---- gather E[idx] fp32 and write Zq to out[1 + b*262144 + d*4096 + hw]
  {
    int p = t >> 2, q4 = t & 3;
    int row = idx_l[p];
    const float4* Er = (const float4*)(E + row * 64 + q4 * 16);
    float* op = out + 1 + base + (q4 * 16) * 4096 + p;
    #pragma unroll
    for (int i = 0; i < 4; ++i) {
      float4 v = Er[i];
      op[(i * 4 + 0) * 4096] = v.x;
      op[(i * 4 + 1) * 4096] = v.y;
      op[(i * 4 + 2) * 4096] = v.z;
      op[(i * 4 + 3) * 4096] = v.w;
    }
  }
}

extern "C" void kernel_launch(void* const* d_in, const int* in_sizes, int n_in,
                              void* d_out, int out_size, void* d_ws, size_t ws_size,
                              hipStream_t stream) {
  (void)in_sizes; (void)n_in; (void)out_size; (void)ws_size;
  const float* in = (const float*)d_in[0];   // [32,64,64,64]
  const float* E  = (const float*)d_in[1];   // [512,64]
  float* out = (float*)d_out;                // [1 + 8388608]
  __bf16* E16   = (__bf16*)d_ws;                       // 64 KiB
  float*  enorm = (float*)((char*)d_ws + 65536);       // 2 KiB

  vq_prep<<<32, 256, 0, stream>>>(E, E16, enorm, out);
  vq_main<<<2048, 256, 0, stream>>>(in, E, E16, enorm, out);
}

// Round 2
// 113.097 us; speedup vs baseline: 1.1234x; 1.1234x over previous
//
#include <hip/hip_runtime.h>

// VectorQuantizer fused single-kernel: B=32, D=64, H=64, W=64 -> N=131072 px,
// K=512 codes. out[0] = 1.25*mean((E[idx]-z)^2); out[1..] = Zq in [B,D,H,W].
// Each block: 256 thr (4 waves), wave w owns codes [w*128,(w+1)*128) held as
// MFMA B-fragments in REGISTERS (loaded once from fp32 E), then loops over 4
// pixel-tiles of 64 px: stage Z->LDS bf16, MFMA argmin (dist = e_norm - 2 z.e),
// cross-lane/wave merge via monotonic packed keys, gather E fp32 -> Zq.

typedef __bf16 bf16x8 __attribute__((ext_vector_type(8)));
typedef float  f32x4  __attribute__((ext_vector_type(4)));

#define LOSS_SCALE (1.25f / 8388608.f)   // 1.25 / (N*D)

__global__ __launch_bounds__(256, 2) void vq_fused(const float* __restrict__ in,
                                                   const float* __restrict__ E,
                                                   float* __restrict__ out) {
  __shared__ __bf16 Zl[64 * 72];          // 64 px x 64 dims, rows padded to 72
  __shared__ float  znp[4 * 64];          // per-(wave,px) |z|^2 partials
  __shared__ unsigned keys[4 * 64];       // per-(wave,px) packed (dist,idx)
  __shared__ int    idx_l[64];

  const int t    = threadIdx.x;
  const int lane = t & 63;
  const int w    = t >> 6;                // wave 0..3
  const int m16  = lane & 15, q = lane >> 4;

  // ---- once per block: this wave's 128 codes -> B frags (regs) + e_norm ----
  bf16x8 B0s[8], B1s[8];
  float  en[8];
  const int cbase = w * 128 + m16;        // lane's code column base
  #pragma unroll
  for (int ct = 0; ct < 8; ++ct) {
    int c = cbase + ct * 16;
    const float4* Ea = (const float4*)(E + c * 64 + q * 8);        // dims q*8..
    const float4* Eb = (const float4*)(E + c * 64 + 32 + q * 8);   // dims 32+q*8..
    float4 a0 = Ea[0], a1 = Ea[1], b0 = Eb[0], b1 = Eb[1];
    float f0[8] = {a0.x,a0.y,a0.z,a0.w,a1.x,a1.y,a1.z,a1.w};
    float f1[8] = {b0.x,b0.y,b0.z,b0.w,b1.x,b1.y,b1.z,b1.w};
    float ss = 0.f;
    bf16x8 v0, v1;
    #pragma unroll
    for (int j = 0; j < 8; ++j) {
      ss += f0[j]*f0[j] + f1[j]*f1[j];
      v0[j] = (__bf16)f0[j];
      v1[j] = (__bf16)f1[j];
    }
    ss += __shfl_xor(ss, 16);             // reduce across the 4 q-lanes
    ss += __shfl_xor(ss, 32);
    en[ct] = ss;
    B0s[ct] = v0; B1s[ct] = v1;
  }

  float loss_acc = 0.f;
  const int tb0 = blockIdx.x * 4;

  for (int it = 0; it < 4; ++it) {
    const int tb   = tb0 + it;            // pixel tile 0..2047
    const int bb   = tb >> 6;             // batch
    const int base = bb * 262144 + ((tb & 63) << 6);

    // ---- stage Z tile: pixel = lane, wave w loads dim groups w*8 / (w+4)*8
    {
      float f0[8], f1[8], ss = 0.f;
      #pragma unroll
      for (int j = 0; j < 8; ++j) {
        f0[j] = in[base + (w * 8 + j) * 4096 + lane];
        f1[j] = in[base + ((w + 4) * 8 + j) * 4096 + lane];
      }
      bf16x8 v0, v1;
      #pragma unroll
      for (int j = 0; j < 8; ++j) {
        ss += f0[j]*f0[j] + f1[j]*f1[j];
        v0[j] = (__bf16)f0[j];
        v1[j] = (__bf16)f1[j];
      }
      *(bf16x8*)&Zl[lane * 72 + w * 8]      = v0;
      *(bf16x8*)&Zl[lane * 72 + 32 + w * 8] = v1;
      znp[w * 64 + lane] = ss;
    }
    __syncthreads();

    // ---- A fragments: 4 pixel sub-tiles x 2 k-halves
    bf16x8 A[4][2];
    #pragma unroll
    for (int pt = 0; pt < 4; ++pt) {
      int p = pt * 16 + m16;
      A[pt][0] = *(const bf16x8*)&Zl[p * 72 + q * 8];
      A[pt][1] = *(const bf16x8*)&Zl[p * 72 + 32 + q * 8];
    }

    // packed keys: monotonic uint of dist with low 9 bits = code idx
    unsigned mnk[4][4];
    #pragma unroll
    for (int pt = 0; pt < 4; ++pt)
      #pragma unroll
      for (int r = 0; r < 4; ++r) mnk[pt][r] = 0xFFFFFFFFu;

    #pragma unroll
    for (int ct = 0; ct < 8; ++ct) {
      const unsigned c = (unsigned)(cbase + ct * 16);
      #pragma unroll
      for (int pt = 0; pt < 4; ++pt) {
        f32x4 acc = {0.f, 0.f, 0.f, 0.f};
        acc = __builtin_amdgcn_mfma_f32_16x16x32_bf16(A[pt][0], B0s[ct], acc, 0, 0, 0);
        acc = __builtin_amdgcn_mfma_f32_16x16x32_bf16(A[pt][1], B1s[ct], acc, 0, 0, 0);
        #pragma unroll
        for (int r = 0; r < 4; ++r) {
          float dist = fmaf(-2.f, acc[r], en[ct]);
          unsigned u = __float_as_uint(dist);
          unsigned key = ((u ^ ((unsigned)((int)u >> 31) | 0x80000000u)) & 0xFFFFFE00u) | c;
          mnk[pt][r] = key < mnk[pt][r] ? key : mnk[pt][r];
        }
      }
    }

    // ---- merge across the 16 code-columns (lanes with same q)
    #pragma unroll
    for (int pt = 0; pt < 4; ++pt)
      #pragma unroll
      for (int r = 0; r < 4; ++r) {
        unsigned key = mnk[pt][r];
        #pragma unroll
        for (int off = 1; off < 16; off <<= 1) {
          unsigned o = __shfl_xor(key, off);
          key = o < key ? o : key;
        }
        if (m16 == 0) keys[w * 64 + pt * 16 + q * 4 + r] = key;
      }
    __syncthreads();

    // ---- per-pixel final merge across waves + loss partial (wave 0)
    if (t < 64) {
      unsigned k0 = keys[t], k1 = keys[64 + t], k2 = keys[128 + t], k3 = keys[192 + t];
      unsigned km = k1 < k0 ? k1 : k0;
      unsigned kn = k3 < k2 ? k3 : k2;
      km = kn < km ? kn : km;
      idx_l[t] = (int)(km & 511u);
      unsigned ub = (km >= 0x80000000u) ? (km ^ 0x80000000u) : ~km;
      float dist = __uint_as_float(ub);
      float zn = znp[t] + znp[64 + t] + znp[128 + t] + znp[192 + t];
      loss_acc += zn + dist;              // min_k ||z - e_k||^2
    }
    __syncthreads();

    // ---- gather E[idx] fp32, write Zq to out[1 + b*262144 + d*4096 + hw]
    {
      int p = t >> 2, q4 = t & 3;
      int row = idx_l[p];
      const float4* Er = (const float4*)(E + row * 64 + q4 * 16);
      float* op = out + 1 + base + (q4 * 16) * 4096 + p;
      #pragma unroll
      for (int i = 0; i < 4; ++i) {
        float4 v = Er[i];
        op[(i * 4 + 0) * 4096] = v.x;
        op[(i * 4 + 1) * 4096] = v.y;
        op[(i * 4 + 2) * 4096] = v.z;
        op[(i * 4 + 3) * 4096] = v.w;
      }
    }
  }

  // ---- loss: reduce wave 0, one atomic per block
  if (t < 64) {
    #pragma unroll
    for (int off = 1; off < 64; off <<= 1) loss_acc += __shfl_xor(loss_acc, off);
    if (t == 0) atomicAdd(out, loss_acc * LOSS_SCALE);
  }
}

extern "C" void kernel_launch(void* const* d_in, const int* in_sizes, int n_in,
                              void* d_out, int out_size, void* d_ws, size_t ws_size,
                              hipStream_t stream) {
  (void)in_sizes; (void)n_in; (void)out_size; (void)d_ws; (void)ws_size;
  const float* in = (const float*)d_in[0];   // [32,64,64,64]
  const float* E  = (const float*)d_in[1];   // [512,64]
  float* out = (float*)d_out;                // [1 + 8388608]
  hipMemsetAsync(out, 0, sizeof(float), stream);   // zero the loss accumulator
  vq_fused<<<512, 256, 0, stream>>>(in, E, out);
}